// Round 4
// baseline (18666.960 us; speedup 1.0000x reference)
//
#include <hip/hip_runtime.h>
#include <math.h>

#define GRV 9.80665f

__device__ __forceinline__ void so3coeffs(float a2, float* c1, float* c2, float* c3){
  if (a2 < 2.5e-3f){
    float a4 = a2*a2;
    *c1 = 1.f      - a2*(1.f/6.f)   + a4*(1.f/120.f);
    *c2 = 0.5f     - a2*(1.f/24.f)  + a4*(1.f/720.f);
    *c3 = (1.f/6.f)- a2*(1.f/120.f) + a4*(1.f/5040.f);
  } else {
    float a = sqrtf(a2);
    float sa = sinf(a), ca = cosf(a);
    *c1 = sa/a; *c2 = (1.f-ca)/a2; *c3 = (a-sa)/(a2*a);
  }
}

__device__ __forceinline__ void so3exp_u(float p0, float p1, float p2, float* R){
  float a2 = p0*p0+p1*p1+p2*p2;
  float c1,c2,c3; so3coeffs(a2,&c1,&c2,&c3);
  R[0]=1.f+c2*(p0*p0-a2); R[4]=1.f+c2*(p1*p1-a2); R[8]=1.f+c2*(p2*p2-a2);
  R[1]=-c1*p2+c2*p0*p1;   R[3]= c1*p2+c2*p0*p1;
  R[2]= c1*p1+c2*p0*p2;   R[6]=-c1*p1+c2*p0*p2;
  R[5]=-c1*p0+c2*p1*p2;   R[7]= c1*p0+c2*p1*p2;
}

__device__ __forceinline__ void mat3mul_u(const float* A, const float* B, float* C){
  #pragma unroll
  for (int r=0;r<3;r++)
    #pragma unroll
    for (int c=0;c<3;c++)
      C[r*3+c] = A[r*3]*B[c] + A[r*3+1]*B[3+c] + A[r*3+2]*B[6+c];
}

// a := a + N @ a  (a as 21-elem column; N = F + F^2/2 + F^3/6, F nilpotent)
__device__ __forceinline__ void col_update(float* a, const float* R_, const float* n13,
                                           const float* n23, float dtv, float hdt2,
                                           float Gdt, float Ghdt2){
  float nb[9];
  #pragma unroll
  for (int jb=0;jb<3;jb++)
    nb[jb] = a[jb] - dtv*(R_[jb*3]*a[9]+R_[jb*3+1]*a[10]+R_[jb*3+2]*a[11]);
  #pragma unroll
  for (int r=0;r<3;r++){
    float s = a[3+r];
    if (r==0) s += Gdt*a[1];
    if (r==1) s -= Gdt*a[0];
    s += n13[r*3]*a[9]+n13[r*3+1]*a[10]+n13[r*3+2]*a[11];
    s -= dtv*(R_[r*3]*a[12]+R_[r*3+1]*a[13]+R_[r*3+2]*a[14]);
    nb[3+r]=s;
  }
  #pragma unroll
  for (int r=0;r<3;r++){
    float s = a[6+r];
    if (r==0) s += Ghdt2*a[1];
    if (r==1) s -= Ghdt2*a[0];
    s += dtv*a[3+r];
    s += n23[r*3]*a[9]+n23[r*3+1]*a[10]+n23[r*3+2]*a[11];
    s -= hdt2*(R_[r*3]*a[12]+R_[r*3+1]*a[13]+R_[r*3+2]*a[14]);
    nb[6+r]=s;
  }
  #pragma unroll
  for (int k=0;k<9;k++) a[k]=nb[k];
}

__global__ __launch_bounds__(64)
void iekf_kernel(const float* __restrict__ t, const float* __restrict__ u,
                 const float* __restrict__ mcov, const float* __restrict__ vmes,
                 const float* __restrict__ ang0, const float* __restrict__ winit,
                 float* __restrict__ out, int N)
{
  const int lane = threadIdx.x;

  __shared__ float TP1[21*24];
  __shared__ float TP2[21*24];
  __shared__ float PH[44];
  __shared__ float stG[36];

  float R_[9], v_[3], p_[3], bo_[3], ba_[3], Rci_[9], tci_[3];
  float creg[21];

  // ---------------- init (uniform) ----------------
  float beta[6];
  #pragma unroll
  for (int k=0;k<6;k++) beta[k] = powf(10.f, tanhf(winit[k]));
  {
    float cr=cosf(ang0[0]), sr=sinf(ang0[0]);
    float cp=cosf(ang0[1]), sp=sinf(ang0[1]);
    float cy=cosf(ang0[2]), sy=sinf(ang0[2]);
    float Rz[9]={cy,-sy,0.f, sy,cy,0.f, 0.f,0.f,1.f};
    float Ry[9]={cp,0.f,sp, 0.f,1.f,0.f, -sp,0.f,cp};
    float Rx[9]={1.f,0.f,0.f, 0.f,cr,-sr, 0.f,sr,cr};
    float T1m[9]; mat3mul_u(Rz,Ry,T1m); mat3mul_u(T1m,Rx,R_);
  }
  v_[0]=vmes[0]; v_[1]=vmes[1]; v_[2]=vmes[2];
  #pragma unroll
  for (int k=0;k<3;k++){ p_[k]=0.f; bo_[k]=0.f; ba_[k]=0.f; tci_[k]=0.f; }
  #pragma unroll
  for (int k=0;k<9;k++) Rci_[k] = (k%4==0)?1.f:0.f;

  {
    float dl = (lane==0||lane==1)? 1e-3f*beta[0]
             : (lane==3||lane==4)? 0.1f*beta[1]
             : (lane>=9&&lane<12)? 0.1f*beta[2]
             : (lane>=12&&lane<15)? 0.1f*beta[3]
             : (lane>=15&&lane<18)? 1e-6f*beta[4]
             : (lane>=18&&lane<21)? 1e-5f*beta[5] : 0.f;
    #pragma unroll
    for (int j=0;j<21;j++) creg[j] = (j==lane)? dl : 0.f;
  }

  if (lane==0){
    ((float4*)stG)[0] = make_float4(R_[0],R_[1],R_[2],R_[3]);
    ((float4*)stG)[1] = make_float4(R_[4],R_[5],R_[6],R_[7]);
    ((float4*)stG)[2] = make_float4(R_[8],v_[0],v_[1],v_[2]);
    ((float4*)stG)[3] = make_float4(p_[0],p_[1],p_[2],bo_[0]);
    ((float4*)stG)[4] = make_float4(bo_[1],bo_[2],ba_[0],ba_[1]);
    ((float4*)stG)[5] = make_float4(ba_[2],Rci_[0],Rci_[1],Rci_[2]);
    ((float4*)stG)[6] = make_float4(Rci_[3],Rci_[4],Rci_[5],Rci_[6]);
    ((float4*)stG)[7] = make_float4(Rci_[7],Rci_[8],tci_[0],tci_[1]);
    ((float4*)stG)[8] = make_float4(tci_[2],0.f,0.f,0.f);
  }

  // double-buffered prefetch (uniform addresses -> scalar loads)
  float t_nm1 = t[0];
  float t_n   = (N>1)? t[1] : t[0];
  float t_np  = (N>2)? t[2] : t_n;
  float mc0   = (N>1)? mcov[2] : 0.f;
  float mc1   = (N>1)? mcov[3] : 0.f;
  float mc0b  = (N>2)? mcov[4] : 0.f;
  float mc1b  = (N>2)? mcov[5] : 0.f;
  float u6[6] = {0,0,0,0,0,0}, u6b[6] = {0,0,0,0,0,0};
  if (N>1){
    #pragma unroll
    for (int k=0;k<6;k++) u6[k]=u[6+k];
  }
  if (N>2){
    #pragma unroll
    for (int k=0;k<6;k++) u6b[k]=u[12+k];
  }

  for (int n=1; n<N; n++){
    const float dtv = t_n - t_nm1;
    const float dt2 = dtv*dtv;
    const float hdt2 = 0.5f*dt2;
    const float sdt3 = dt2*dtv*(1.f/6.f);
    const float Gdt = GRV*dtv;
    const float Ghdt2 = GRV*hdt2;

    // ---- stream out row n-1 (state from prev iter via stG) ----
    if (lane<33) out[(size_t)(n-1)*33 + lane] = stG[lane];

    // ---- T1 write: P rows -> LDS ----
    if (lane<21){
      float4* rp = (float4*)&TP1[lane*24];
      rp[0]=make_float4(creg[0],creg[1],creg[2],creg[3]);
      rp[1]=make_float4(creg[4],creg[5],creg[6],creg[7]);
      rp[2]=make_float4(creg[8],creg[9],creg[10],creg[11]);
      rp[3]=make_float4(creg[12],creg[13],creg[14],creg[15]);
      rp[4]=make_float4(creg[16],creg[17],creg[18],creg[19]);
      TP1[lane*24+20]=creg[20];
    }

    // ---- uniform small algebra ----
    float vsr[9], psr[9], n13[9], n23[9];
    #pragma unroll
    for (int c=0;c<3;c++){
      vsr[c]   = v_[1]*R_[6+c] - v_[2]*R_[3+c];
      vsr[3+c] = v_[2]*R_[c]   - v_[0]*R_[6+c];
      vsr[6+c] = v_[0]*R_[3+c] - v_[1]*R_[c];
      psr[c]   = p_[1]*R_[6+c] - p_[2]*R_[3+c];
      psr[3+c] = p_[2]*R_[c]   - p_[0]*R_[6+c];
      psr[6+c] = p_[0]*R_[3+c] - p_[1]*R_[c];
    }
    #pragma unroll
    for (int c=0;c<3;c++){
      float sg0 =  GRV*R_[3+c];
      float sg1 = -GRV*R_[c];
      n13[c]   = -dtv*vsr[c]   - hdt2*sg0;
      n13[3+c] = -dtv*vsr[3+c] - hdt2*sg1;
      n13[6+c] = -dtv*vsr[6+c];
      n23[c]   = -dtv*psr[c]   - hdt2*vsr[c]   - sdt3*sg0;
      n23[3+c] = -dtv*psr[3+c] - hdt2*vsr[3+c] - sdt3*sg1;
      n23[6+c] = -dtv*psr[6+c] - hdt2*vsr[6+c];
    }
    const float vv = v_[0]*v_[0]+v_[1]*v_[1]+v_[2]*v_[2];
    const float vp = v_[0]*p_[0]+v_[1]*p_[1]+v_[2]*p_[2];
    const float pp = p_[0]*p_[0]+p_[1]*p_[1]+p_[2]*p_[2];

    // ---- uniform propagate ----
    float Rn[9], vnp[3], pnp[3];
    {
      float ub0=u6[3]-ba_[0], ub1=u6[4]-ba_[1], ub2=u6[5]-ba_[2];
      float ac0=R_[0]*ub0+R_[1]*ub1+R_[2]*ub2;
      float ac1=R_[3]*ub0+R_[4]*ub1+R_[5]*ub2;
      float ac2=R_[6]*ub0+R_[7]*ub1+R_[8]*ub2 - GRV;
      vnp[0]=v_[0]+ac0*dtv; vnp[1]=v_[1]+ac1*dtv; vnp[2]=v_[2]+ac2*dtv;
      pnp[0]=p_[0]+v_[0]*dtv+0.5f*ac0*dt2;
      pnp[1]=p_[1]+v_[1]*dtv+0.5f*ac1*dt2;
      pnp[2]=p_[2]+v_[2]*dtv+0.5f*ac2*dt2;
      float E[9]; so3exp_u((u6[0]-bo_[0])*dtv,(u6[1]-bo_[1])*dtv,(u6[2]-bo_[2])*dtv, E);
      mat3mul_u(R_, E, Rn);
    }
    // ---- H (sparse: 12 nz cols, 4 of them zero-valued) + r ----
    float h0_3,h0_4,h0_5,h0_9,h0_11,h0_15,h0_16,h0_17,h0_18,h0_20;
    float h1_3,h1_4,h1_5,h1_9,h1_10,h1_15,h1_16,h1_17,h1_18,h1_19;
    float rsh0, rsh1;
    {
      float Rb[9]; mat3mul_u(Rn, Rci_, Rb);
      float vi0 = Rn[0]*vnp[0]+Rn[3]*vnp[1]+Rn[6]*vnp[2];
      float vi1 = Rn[1]*vnp[0]+Rn[4]*vnp[1]+Rn[7]*vnp[2];
      float vi2 = Rn[2]*vnp[0]+Rn[5]*vnp[1]+Rn[8]*vnp[2];
      float o0 = u6[0]-bo_[0], o1 = u6[1]-bo_[1], o2 = u6[2]-bo_[2];
      h0_3 = Rb[1]; h0_4 = Rb[4]; h0_5 = Rb[7];
      h1_3 = Rb[2]; h1_4 = Rb[5]; h1_5 = Rb[8];
      h0_9 = tci_[2];  h0_11 = -tci_[0];
      h1_9 = -tci_[1]; h1_10 = tci_[0];
      h0_15 =  Rci_[4]*vi2 - Rci_[7]*vi1;
      h0_16 = -Rci_[1]*vi2 + Rci_[7]*vi0;
      h0_17 =  Rci_[1]*vi1 - Rci_[4]*vi0;
      h1_15 =  Rci_[5]*vi2 - Rci_[8]*vi1;
      h1_16 = -Rci_[2]*vi2 + Rci_[8]*vi0;
      h1_17 =  Rci_[2]*vi1 - Rci_[5]*vi0;
      h0_18 = -o2; h0_20 = o0;
      h1_18 =  o1; h1_19 = -o0;
      rsh0 = -( Rci_[1]*vi0 + Rci_[4]*vi1 + Rci_[7]*vi2 + (tci_[2]*o0 - tci_[0]*o2) );
      rsh1 = -( Rci_[2]*vi0 + Rci_[5]*vi1 + Rci_[8]*vi2 + (-tci_[1]*o0 + tci_[0]*o1) );
    }

    // ---- T1 col read + sym avg -> areg ----
    float areg[21];
    if (lane<21){
      #pragma unroll
      for (int j=0;j<21;j++) areg[j] = 0.5f*(creg[j] + TP1[j*24+lane]);
    } else {
      #pragma unroll
      for (int j=0;j<21;j++) areg[j] = 0.f;
    }
    // ---- closed-form GQG^T add ----
    {
      const float qom = 1e-3f*dt2, qac = 1e-2f*dt2;
      if (lane<9){
        int bi = lane/3, r3 = lane - 3*bi;
        float vrr = (r3==0)?v_[0]:(r3==1)?v_[1]:v_[2];
        float prr = (r3==0)?p_[0]:(r3==1)?p_[1]:p_[2];
        // row r3 of skew(v), skew(p)
        float sv0 = (r3==0)?0.f:(r3==1)? v_[2]:-v_[1];
        float sv1 = (r3==0)?-v_[2]:(r3==1)?0.f: v_[0];
        float sv2 = (r3==0)? v_[1]:(r3==1)?-v_[0]:0.f;
        float sp0 = (r3==0)?0.f:(r3==1)? p_[2]:-p_[1];
        float sp1 = (r3==0)?-p_[2]:(r3==1)?0.f: p_[0];
        float sp2 = (r3==0)? p_[1]:(r3==1)?-p_[0]:0.f;
        if (bi==0){
          areg[r3]  += qom;
          areg[3] -= qom*sv0; areg[4] -= qom*sv1; areg[5] -= qom*sv2;
          areg[6] -= qom*sp0; areg[7] -= qom*sp1; areg[8] -= qom*sp2;
        } else if (bi==1){
          areg[0] += qom*sv0; areg[1] += qom*sv1; areg[2] += qom*sv2;
          areg[3+r3] += qom*vv + qac;
          areg[3] -= qom*vrr*v_[0]; areg[4] -= qom*vrr*v_[1]; areg[5] -= qom*vrr*v_[2];
          areg[6+r3] += qom*vp;
          areg[6] -= qom*prr*v_[0]; areg[7] -= qom*prr*v_[1]; areg[8] -= qom*prr*v_[2];
        } else {
          areg[0] += qom*sp0; areg[1] += qom*sp1; areg[2] += qom*sp2;
          areg[3+r3] += qom*vp;
          areg[3] -= qom*vrr*p_[0]; areg[4] -= qom*vrr*p_[1]; areg[5] -= qom*vrr*p_[2];
          areg[6+r3] += qom*pp;
          areg[6] -= qom*prr*p_[0]; areg[7] -= qom*prr*p_[1]; areg[8] -= qom*prr*p_[2];
        }
      } else if (lane<21){
        float qd = (lane<12)? 6e-9f : (lane<15)? 2e-4f : 1e-9f;
        areg[lane] += qd*dt2;
      }
    }

    // ---- U1: X = A(I+N^T) row-wise ----
    col_update(areg, R_, n13, n23, dtv, hdt2, Gdt, Ghdt2);

    // ---- y = X H^T per-lane (treed, sparse) ----
    float y0 = (((areg[3]*h0_3 + areg[4]*h0_4) + (areg[5]*h0_5 + areg[9]*h0_9)) +
                ((areg[11]*h0_11 + areg[15]*h0_15) + (areg[16]*h0_16 + areg[17]*h0_17))) +
               (areg[18]*h0_18 + areg[20]*h0_20);
    float y1 = (((areg[3]*h1_3 + areg[4]*h1_4) + (areg[5]*h1_5 + areg[9]*h1_9)) +
                ((areg[10]*h1_10 + areg[15]*h1_15) + (areg[16]*h1_16 + areg[17]*h1_17))) +
               (areg[18]*h1_18 + areg[19]*h1_19);
    if (lane<21) *(float2*)&PH[lane*2] = make_float2(y0, y1);

    // ---- T2 write X (for the U2 path) ----
    if (lane<21){
      float4* rp = (float4*)&TP2[lane*24];
      rp[0]=make_float4(areg[0],areg[1],areg[2],areg[3]);
      rp[1]=make_float4(areg[4],areg[5],areg[6],areg[7]);
      rp[2]=make_float4(areg[8],areg[9],areg[10],areg[11]);
      rp[3]=make_float4(areg[12],areg[13],areg[14],areg[15]);
      rp[4]=make_float4(areg[16],areg[17],areg[18],areg[19]);
      TP2[lane*24+20]=areg[20];
    }

    // ---- PH read (uniform broadcast) ----
    float y0v[21], y1v[21];
    {
      #pragma unroll
      for (int q=0;q<11;q++){
        float4 v4 = ((float4*)PH)[q];
        if (2*q   < 21){ y0v[2*q]   = v4.x; y1v[2*q]   = v4.y; }
        if (2*q+1 < 21){ y0v[2*q+1] = v4.z; y1v[2*q+1] = v4.w; }
      }
    }
    // ---- T2 read (issued now; consumed after S-chain -> latency hidden) ----
    float ctreg[21];
    if (lane<21){
      #pragma unroll
      for (int r=0;r<21;r++) ctreg[r] = TP2[r*24+lane];
    } else {
      #pragma unroll
      for (int r=0;r<21;r++) ctreg[r] = 0.f;
    }

    // ---- PHt = (I+N) y  (uniform, both columns) ----
    col_update(y0v, R_, n13, n23, dtv, hdt2, Gdt, Ghdt2);
    col_update(y1v, R_, n13, n23, dtv, hdt2, Gdt, Ghdt2);

    // ---- S, inverse, gains (uniform, treed sparse dots) ----
    float s00 = mc0 + ((((h0_3*y0v[3] + h0_4*y0v[4]) + (h0_5*y0v[5] + h0_9*y0v[9])) +
                        ((h0_11*y0v[11] + h0_15*y0v[15]) + (h0_16*y0v[16] + h0_17*y0v[17]))) +
                       (h0_18*y0v[18] + h0_20*y0v[20]));
    float s01 =        ((((h0_3*y1v[3] + h0_4*y1v[4]) + (h0_5*y1v[5] + h0_9*y1v[9])) +
                        ((h0_11*y1v[11] + h0_15*y1v[15]) + (h0_16*y1v[16] + h0_17*y1v[17]))) +
                       (h0_18*y1v[18] + h0_20*y1v[20]));
    float s10 =        ((((h1_3*y0v[3] + h1_4*y0v[4]) + (h1_5*y0v[5] + h1_9*y0v[9])) +
                        ((h1_10*y0v[10] + h1_15*y0v[15]) + (h1_16*y0v[16] + h1_17*y0v[17]))) +
                       (h1_18*y0v[18] + h1_19*y0v[19]));
    float s11 = mc1 + ((((h1_3*y1v[3] + h1_4*y1v[4]) + (h1_5*y1v[5] + h1_9*y1v[9])) +
                        ((h1_10*y1v[10] + h1_15*y1v[15]) + (h1_16*y1v[16] + h1_17*y1v[17]))) +
                       (h1_18*y1v[18] + h1_19*y1v[19]));
    float id  = 1.f/(s00*s11 - s01*s10);
    float i00 =  s11*id, i01 = -s01*id, i10 = -s10*id, i11 = s00*id;
    float sm01 = 0.5f*(s01+s10);
    float g0 = i00*rsh0 + i01*rsh1;
    float g1 = i10*rsh0 + i11*rsh1;

    // ---- dx (uniform) ----
    float dx[21];
    #pragma unroll
    for (int j=0;j<21;j++) dx[j] = y0v[j]*g0 + y1v[j]*g1;

    // ---- U2: rows of P_pred ----
    col_update(ctreg, R_, n13, n23, dtv, hdt2, Gdt, Ghdt2);

    // ---- per-lane ph, alpha/beta; rank-2 fold ----
    {
      float ph0 = (((ctreg[3]*h0_3 + ctreg[4]*h0_4) + (ctreg[5]*h0_5 + ctreg[9]*h0_9)) +
                   ((ctreg[11]*h0_11 + ctreg[15]*h0_15) + (ctreg[16]*h0_16 + ctreg[17]*h0_17))) +
                  (ctreg[18]*h0_18 + ctreg[20]*h0_20);
      float ph1 = (((ctreg[3]*h1_3 + ctreg[4]*h1_4) + (ctreg[5]*h1_5 + ctreg[9]*h1_9)) +
                   ((ctreg[10]*h1_10 + ctreg[15]*h1_15) + (ctreg[16]*h1_16 + ctreg[17]*h1_17))) +
                  (ctreg[18]*h1_18 + ctreg[19]*h1_19);
      float ki0 = ph0*i00 + ph1*i10;
      float ki1 = ph0*i01 + ph1*i11;
      float ai0 = s00*ki0 + sm01*ki1;
      float ai1 = sm01*ki0 + s11*ki1;
      float al = -ki0 + (ai0 - ph0)*i00 + (ai1 - ph1)*i01;
      float be = -ki1 + (ai0 - ph0)*i10 + (ai1 - ph1)*i11;
      #pragma unroll
      for (int j=0;j<21;j++) creg[j] = ctreg[j] + al*y0v[j] + be*y1v[j];
    }

    // ---- retraction (uniform) ----
    {
      float q0=dx[0], q1=dx[1], q2=dx[2];
      float a2 = q0*q0+q1*q1+q2*q2;
      float c1,c2,c3; so3coeffs(a2,&c1,&c2,&c3);
      float dR[9], Jm[9];
      dR[0]=1.f+c2*(q0*q0-a2); dR[4]=1.f+c2*(q1*q1-a2); dR[8]=1.f+c2*(q2*q2-a2);
      dR[1]=-c1*q2+c2*q0*q1;   dR[3]= c1*q2+c2*q0*q1;
      dR[2]= c1*q1+c2*q0*q2;   dR[6]=-c1*q1+c2*q0*q2;
      dR[5]=-c1*q0+c2*q1*q2;   dR[7]= c1*q0+c2*q1*q2;
      Jm[0]=1.f+c3*(q0*q0-a2); Jm[4]=1.f+c3*(q1*q1-a2); Jm[8]=1.f+c3*(q2*q2-a2);
      Jm[1]=-c2*q2+c3*q0*q1;   Jm[3]= c2*q2+c3*q0*q1;
      Jm[2]= c2*q1+c3*q0*q2;   Jm[6]=-c2*q1+c3*q0*q2;
      Jm[5]=-c2*q0+c3*q1*q2;   Jm[7]= c2*q0+c3*q1*q2;
      float xv[3], xp[3];
      #pragma unroll
      for (int r=0;r<3;r++){
        xv[r]=Jm[r*3]*dx[3]+Jm[r*3+1]*dx[4]+Jm[r*3+2]*dx[5];
        xp[r]=Jm[r*3]*dx[6]+Jm[r*3+1]*dx[7]+Jm[r*3+2]*dx[8];
      }
      float Rn2[9]; mat3mul_u(dR, Rn, Rn2);
      #pragma unroll
      for (int r=0;r<3;r++){
        float vv2 = dR[r*3]*vnp[0]+dR[r*3+1]*vnp[1]+dR[r*3+2]*vnp[2] + xv[r];
        float pp2 = dR[r*3]*pnp[0]+dR[r*3+1]*pnp[1]+dR[r*3+2]*pnp[2] + xp[r];
        v_[r]=vv2; p_[r]=pp2;
        bo_[r]+=dx[9+r]; ba_[r]+=dx[12+r]; tci_[r]+=dx[18+r];
      }
      float E2[9]; so3exp_u(dx[15],dx[16],dx[17],E2);
      float Rc2[9]; mat3mul_u(E2, Rci_, Rc2);
      #pragma unroll
      for (int k=0;k<9;k++){ Rci_[k]=Rc2[k]; R_[k]=Rn2[k]; }
    }
    // commit state (lane 0)
    if (lane==0){
      ((float4*)stG)[0] = make_float4(R_[0],R_[1],R_[2],R_[3]);
      ((float4*)stG)[1] = make_float4(R_[4],R_[5],R_[6],R_[7]);
      ((float4*)stG)[2] = make_float4(R_[8],v_[0],v_[1],v_[2]);
      ((float4*)stG)[3] = make_float4(p_[0],p_[1],p_[2],bo_[0]);
      ((float4*)stG)[4] = make_float4(bo_[1],bo_[2],ba_[0],ba_[1]);
      ((float4*)stG)[5] = make_float4(ba_[2],Rci_[0],Rci_[1],Rci_[2]);
      ((float4*)stG)[6] = make_float4(Rci_[3],Rci_[4],Rci_[5],Rci_[6]);
      ((float4*)stG)[7] = make_float4(Rci_[7],Rci_[8],tci_[0],tci_[1]);
      ((float4*)stG)[8] = make_float4(tci_[2],0.f,0.f,0.f);
    }

    // ---- shift prefetch buffers, load 2-ahead ----
    {
      t_nm1 = t_n; t_n = t_np;
      mc0 = mc0b; mc1 = mc1b;
      #pragma unroll
      for (int k=0;k<6;k++) u6[k]=u6b[k];
      int np2 = n+2;
      if (np2 < N){
        t_np = t[np2];
        mc0b = mcov[np2*2]; mc1b = mcov[np2*2+1];
        #pragma unroll
        for (int k=0;k<6;k++) u6b[k]=u[np2*6+k];
      }
    }
  }

  // final output row
  if (lane<33) out[(size_t)(N-1)*33 + lane] = stG[lane];
}

extern "C" void kernel_launch(void* const* d_in, const int* in_sizes, int n_in,
                              void* d_out, int out_size, void* d_ws, size_t ws_size,
                              hipStream_t stream) {
  const float* t     = (const float*)d_in[0];
  const float* u     = (const float*)d_in[1];
  const float* mcov  = (const float*)d_in[2];
  const float* vmes  = (const float*)d_in[3];
  // d_in[4] = p_mes (unused by reference)
  const float* ang0  = (const float*)d_in[5];
  const float* winit = (const float*)d_in[6];
  float* out = (float*)d_out;
  int N = in_sizes[0];
  iekf_kernel<<<dim3(1), dim3(64), 0, stream>>>(t, u, mcov, vmes, ang0, winit, out, N);
}

// Round 5
// 14808.879 us; speedup vs baseline: 1.2605x; 1.2605x over previous
//
#include <hip/hip_runtime.h>
#include <math.h>

#define GRV 9.80665f

__device__ __forceinline__ void so3coeffs(float a2, float* c1, float* c2, float* c3){
  if (a2 < 2.5e-3f){
    float a4 = a2*a2;
    *c1 = 1.f      - a2*(1.f/6.f)   + a4*(1.f/120.f);
    *c2 = 0.5f     - a2*(1.f/24.f)  + a4*(1.f/720.f);
    *c3 = (1.f/6.f)- a2*(1.f/120.f) + a4*(1.f/5040.f);
  } else {
    float a = sqrtf(a2);
    float sa = sinf(a), ca = cosf(a);
    *c1 = sa/a; *c2 = (1.f-ca)/a2; *c3 = (a-sa)/(a2*a);
  }
}

__device__ __forceinline__ void so3exp_u(float p0, float p1, float p2, float* R){
  float a2 = p0*p0+p1*p1+p2*p2;
  float c1,c2,c3; so3coeffs(a2,&c1,&c2,&c3);
  R[0]=1.f+c2*(p0*p0-a2); R[4]=1.f+c2*(p1*p1-a2); R[8]=1.f+c2*(p2*p2-a2);
  R[1]=-c1*p2+c2*p0*p1;   R[3]= c1*p2+c2*p0*p1;
  R[2]= c1*p1+c2*p0*p2;   R[6]=-c1*p1+c2*p0*p2;
  R[5]=-c1*p0+c2*p1*p2;   R[7]= c1*p0+c2*p1*p2;
}

__device__ __forceinline__ void mat3mul_u(const float* A, const float* B, float* C){
  #pragma unroll
  for (int r=0;r<3;r++)
    #pragma unroll
    for (int c=0;c<3;c++)
      C[r*3+c] = A[r*3]*B[c] + A[r*3+1]*B[3+c] + A[r*3+2]*B[6+c];
}

// a := a + N @ a  (a as 21-elem column; N = F + F^2/2 + F^3/6, F nilpotent)
__device__ __forceinline__ void col_update(float* a, const float* R_, const float* n13,
                                           const float* n23, float dtv, float hdt2,
                                           float Gdt, float Ghdt2){
  float nb[9];
  #pragma unroll
  for (int jb=0;jb<3;jb++)
    nb[jb] = a[jb] - dtv*(R_[jb*3]*a[9]+R_[jb*3+1]*a[10]+R_[jb*3+2]*a[11]);
  #pragma unroll
  for (int r=0;r<3;r++){
    float s = a[3+r];
    if (r==0) s += Gdt*a[1];
    if (r==1) s -= Gdt*a[0];
    s += n13[r*3]*a[9]+n13[r*3+1]*a[10]+n13[r*3+2]*a[11];
    s -= dtv*(R_[r*3]*a[12]+R_[r*3+1]*a[13]+R_[r*3+2]*a[14]);
    nb[3+r]=s;
  }
  #pragma unroll
  for (int r=0;r<3;r++){
    float s = a[6+r];
    if (r==0) s += Ghdt2*a[1];
    if (r==1) s -= Ghdt2*a[0];
    s += dtv*a[3+r];
    s += n23[r*3]*a[9]+n23[r*3+1]*a[10]+n23[r*3+2]*a[11];
    s -= hdt2*(R_[r*3]*a[12]+R_[r*3+1]*a[13]+R_[r*3+2]*a[14]);
    nb[6+r]=s;
  }
  #pragma unroll
  for (int k=0;k<9;k++) a[k]=nb[k];
}

#define SEL9(e0,e1,e2,e3,e4,e5,e6,e7,e8) \
  (lane==0?(e0):lane==1?(e1):lane==2?(e2):lane==3?(e3):lane==4?(e4):lane==5?(e5):lane==6?(e6):lane==7?(e7):(e8))

__global__ __launch_bounds__(64)
void iekf_kernel(const float* __restrict__ t, const float* __restrict__ u,
                 const float* __restrict__ mcov, const float* __restrict__ vmes,
                 const float* __restrict__ ang0, const float* __restrict__ winit,
                 float* __restrict__ out, int N)
{
  const int lane = threadIdx.x;

  __shared__ float TP1[21*24];
  __shared__ float TP2[21*24];
  __shared__ float PH[44];
  __shared__ float stG[36];

  float R_[9], v_[3], p_[3], bo_[3], ba_[3], Rci_[9], tci_[3];
  float creg[21];

  // ---------------- init (uniform) ----------------
  float beta[6];
  #pragma unroll
  for (int k=0;k<6;k++) beta[k] = powf(10.f, tanhf(winit[k]));
  {
    float cr=cosf(ang0[0]), sr=sinf(ang0[0]);
    float cp=cosf(ang0[1]), sp=sinf(ang0[1]);
    float cy=cosf(ang0[2]), sy=sinf(ang0[2]);
    float Rz[9]={cy,-sy,0.f, sy,cy,0.f, 0.f,0.f,1.f};
    float Ry[9]={cp,0.f,sp, 0.f,1.f,0.f, -sp,0.f,cp};
    float Rx[9]={1.f,0.f,0.f, 0.f,cr,-sr, 0.f,sr,cr};
    float T1m[9]; mat3mul_u(Rz,Ry,T1m); mat3mul_u(T1m,Rx,R_);
  }
  v_[0]=vmes[0]; v_[1]=vmes[1]; v_[2]=vmes[2];
  #pragma unroll
  for (int k=0;k<3;k++){ p_[k]=0.f; bo_[k]=0.f; ba_[k]=0.f; tci_[k]=0.f; }
  #pragma unroll
  for (int k=0;k<9;k++) Rci_[k] = (k%4==0)?1.f:0.f;

  {
    float dl = (lane==0||lane==1)? 1e-3f*beta[0]
             : (lane==3||lane==4)? 0.1f*beta[1]
             : (lane>=9&&lane<12)? 0.1f*beta[2]
             : (lane>=12&&lane<15)? 0.1f*beta[3]
             : (lane>=15&&lane<18)? 1e-6f*beta[4]
             : (lane>=18&&lane<21)? 1e-5f*beta[5] : 0.f;
    #pragma unroll
    for (int j=0;j<21;j++) creg[j] = (j==lane)? dl : 0.f;
  }

  if (lane==0){
    ((float4*)stG)[0] = make_float4(R_[0],R_[1],R_[2],R_[3]);
    ((float4*)stG)[1] = make_float4(R_[4],R_[5],R_[6],R_[7]);
    ((float4*)stG)[2] = make_float4(R_[8],v_[0],v_[1],v_[2]);
    ((float4*)stG)[3] = make_float4(p_[0],p_[1],p_[2],bo_[0]);
    ((float4*)stG)[4] = make_float4(bo_[1],bo_[2],ba_[0],ba_[1]);
    ((float4*)stG)[5] = make_float4(ba_[2],Rci_[0],Rci_[1],Rci_[2]);
    ((float4*)stG)[6] = make_float4(Rci_[3],Rci_[4],Rci_[5],Rci_[6]);
    ((float4*)stG)[7] = make_float4(Rci_[7],Rci_[8],tci_[0],tci_[1]);
    ((float4*)stG)[8] = make_float4(tci_[2],0.f,0.f,0.f);
  }

  // single-ahead prefetch (uniform)
  float t_nm1 = t[0];
  float t_n   = (N>1)? t[1] : t[0];
  float mc0   = (N>1)? mcov[2] : 0.f;
  float mc1   = (N>1)? mcov[3] : 0.f;
  float u6[6] = {0,0,0,0,0,0};
  if (N>1){
    #pragma unroll
    for (int k=0;k<6;k++) u6[k]=u[6+k];
  }

  for (int n=1; n<N; n++){
    const float dtv = t_n - t_nm1;
    const float dt2 = dtv*dtv;
    const float hdt2 = 0.5f*dt2;
    const float sdt3 = dt2*dtv*(1.f/6.f);
    const float Gdt = GRV*dtv;
    const float Ghdt2 = GRV*hdt2;

    // ---- stream out row n-1 ----
    if (lane<33) out[(size_t)(n-1)*33 + lane] = stG[lane];

    // ---- T1 write: P rows -> LDS ----
    if (lane<21){
      float4* rp = (float4*)&TP1[lane*24];
      rp[0]=make_float4(creg[0],creg[1],creg[2],creg[3]);
      rp[1]=make_float4(creg[4],creg[5],creg[6],creg[7]);
      rp[2]=make_float4(creg[8],creg[9],creg[10],creg[11]);
      rp[3]=make_float4(creg[12],creg[13],creg[14],creg[15]);
      rp[4]=make_float4(creg[16],creg[17],creg[18],creg[19]);
      TP1[lane*24+20]=creg[20];
    }

    // ---- uniform small algebra ----
    float vsr[9], psr[9], n13[9], n23[9];
    #pragma unroll
    for (int c=0;c<3;c++){
      vsr[c]   = v_[1]*R_[6+c] - v_[2]*R_[3+c];
      vsr[3+c] = v_[2]*R_[c]   - v_[0]*R_[6+c];
      vsr[6+c] = v_[0]*R_[3+c] - v_[1]*R_[c];
      psr[c]   = p_[1]*R_[6+c] - p_[2]*R_[3+c];
      psr[3+c] = p_[2]*R_[c]   - p_[0]*R_[6+c];
      psr[6+c] = p_[0]*R_[3+c] - p_[1]*R_[c];
    }
    #pragma unroll
    for (int c=0;c<3;c++){
      float sg0 =  GRV*R_[3+c];
      float sg1 = -GRV*R_[c];
      n13[c]   = -dtv*vsr[c]   - hdt2*sg0;
      n13[3+c] = -dtv*vsr[3+c] - hdt2*sg1;
      n13[6+c] = -dtv*vsr[6+c];
      n23[c]   = -dtv*psr[c]   - hdt2*vsr[c]   - sdt3*sg0;
      n23[3+c] = -dtv*psr[3+c] - hdt2*vsr[3+c] - sdt3*sg1;
      n23[6+c] = -dtv*psr[6+c] - hdt2*vsr[6+c];
    }

    // ---- uniform propagate ----
    float Rn[9], vnp[3], pnp[3];
    {
      float ub0=u6[3]-ba_[0], ub1=u6[4]-ba_[1], ub2=u6[5]-ba_[2];
      float ac0=R_[0]*ub0+R_[1]*ub1+R_[2]*ub2;
      float ac1=R_[3]*ub0+R_[4]*ub1+R_[5]*ub2;
      float ac2=R_[6]*ub0+R_[7]*ub1+R_[8]*ub2 - GRV;
      vnp[0]=v_[0]+ac0*dtv; vnp[1]=v_[1]+ac1*dtv; vnp[2]=v_[2]+ac2*dtv;
      pnp[0]=p_[0]+v_[0]*dtv+0.5f*ac0*dt2;
      pnp[1]=p_[1]+v_[1]*dtv+0.5f*ac1*dt2;
      pnp[2]=p_[2]+v_[2]*dtv+0.5f*ac2*dt2;
      float E[9]; so3exp_u((u6[0]-bo_[0])*dtv,(u6[1]-bo_[1])*dtv,(u6[2]-bo_[2])*dtv, E);
      mat3mul_u(R_, E, Rn);
    }
    // ---- H (sparse named regs) + r ----
    float h0_3,h0_4,h0_5,h0_9,h0_11,h0_15,h0_16,h0_17,h0_18,h0_20;
    float h1_3,h1_4,h1_5,h1_9,h1_10,h1_15,h1_16,h1_17,h1_18,h1_19;
    float rsh0, rsh1;
    {
      float Rb[9]; mat3mul_u(Rn, Rci_, Rb);
      float vi0 = Rn[0]*vnp[0]+Rn[3]*vnp[1]+Rn[6]*vnp[2];
      float vi1 = Rn[1]*vnp[0]+Rn[4]*vnp[1]+Rn[7]*vnp[2];
      float vi2 = Rn[2]*vnp[0]+Rn[5]*vnp[1]+Rn[8]*vnp[2];
      float o0 = u6[0]-bo_[0], o1 = u6[1]-bo_[1], o2 = u6[2]-bo_[2];
      h0_3 = Rb[1]; h0_4 = Rb[4]; h0_5 = Rb[7];
      h1_3 = Rb[2]; h1_4 = Rb[5]; h1_5 = Rb[8];
      h0_9 = tci_[2];  h0_11 = -tci_[0];
      h1_9 = -tci_[1]; h1_10 = tci_[0];
      h0_15 =  Rci_[4]*vi2 - Rci_[7]*vi1;
      h0_16 = -Rci_[1]*vi2 + Rci_[7]*vi0;
      h0_17 =  Rci_[1]*vi1 - Rci_[4]*vi0;
      h1_15 =  Rci_[5]*vi2 - Rci_[8]*vi1;
      h1_16 = -Rci_[2]*vi2 + Rci_[8]*vi0;
      h1_17 =  Rci_[2]*vi1 - Rci_[5]*vi0;
      h0_18 = -o2; h0_20 = o0;
      h1_18 =  o1; h1_19 = -o0;
      rsh0 = -( Rci_[1]*vi0 + Rci_[4]*vi1 + Rci_[7]*vi2 + (tci_[2]*o0 - tci_[0]*o2) );
      rsh1 = -( Rci_[2]*vi0 + Rci_[5]*vi1 + Rci_[8]*vi2 + (-tci_[1]*o0 + tci_[0]*o1) );
    }

    // ---- T1 col read + sym avg -> areg ----
    float areg[21];
    if (lane<21){
      #pragma unroll
      for (int j=0;j<21;j++) areg[j] = 0.5f*(creg[j] + TP1[j*24+lane]);
    } else {
      #pragma unroll
      for (int j=0;j<21;j++) areg[j] = 0.f;
    }
    // ---- GQG^T add (R3 version) ----
    {
      const float qom = 1e-3f*dt2, qac = 1e-2f*dt2;
      if (lane<9){
        float wi0 = SEL9(R_[0],R_[3],R_[6], vsr[0],vsr[3],vsr[6], psr[0],psr[3],psr[6]);
        float wi1 = SEL9(R_[1],R_[4],R_[7], vsr[1],vsr[4],vsr[7], psr[1],psr[4],psr[7]);
        float wi2 = SEL9(R_[2],R_[5],R_[8], vsr[2],vsr[5],vsr[8], psr[2],psr[5],psr[8]);
        #pragma unroll
        for (int jq=0;jq<9;jq++){
          float wj0 = (jq<3)? R_[jq*3]   : (jq<6)? vsr[(jq-3)*3]   : psr[(jq-6)*3];
          float wj1 = (jq<3)? R_[jq*3+1] : (jq<6)? vsr[(jq-3)*3+1] : psr[(jq-6)*3+1];
          float wj2 = (jq<3)? R_[jq*3+2] : (jq<6)? vsr[(jq-3)*3+2] : psr[(jq-6)*3+2];
          areg[jq] += qom*(wi0*wj0+wi1*wj1+wi2*wj2);
        }
        if (lane>=3 && lane<6){
          float ri0 = (lane==3)?R_[0]:(lane==4)?R_[3]:R_[6];
          float ri1 = (lane==3)?R_[1]:(lane==4)?R_[4]:R_[7];
          float ri2 = (lane==3)?R_[2]:(lane==4)?R_[5]:R_[8];
          areg[3] += qac*(ri0*R_[0]+ri1*R_[1]+ri2*R_[2]);
          areg[4] += qac*(ri0*R_[3]+ri1*R_[4]+ri2*R_[5]);
          areg[5] += qac*(ri0*R_[6]+ri1*R_[7]+ri2*R_[8]);
        }
      }
      float qd = (lane>=9&&lane<12)? 6e-9f : (lane>=12&&lane<15)? 2e-4f : (lane>=15&&lane<21)? 1e-9f : 0.f;
      qd *= dt2;
      #pragma unroll
      for (int j=9;j<21;j++) if (j==lane) areg[j] += qd;
    }

    // ---- U1: X = A(I+N^T) row-wise ----
    col_update(areg, R_, n13, n23, dtv, hdt2, Gdt, Ghdt2);

    // ---- T2: transpose X ----
    if (lane<21){
      float4* rp = (float4*)&TP2[lane*24];
      rp[0]=make_float4(areg[0],areg[1],areg[2],areg[3]);
      rp[1]=make_float4(areg[4],areg[5],areg[6],areg[7]);
      rp[2]=make_float4(areg[8],areg[9],areg[10],areg[11]);
      rp[3]=make_float4(areg[12],areg[13],areg[14],areg[15]);
      rp[4]=make_float4(areg[16],areg[17],areg[18],areg[19]);
      TP2[lane*24+20]=areg[20];
    }
    float ctreg[21];
    if (lane<21){
      #pragma unroll
      for (int r=0;r<21;r++) ctreg[r] = TP2[r*24+lane];
    } else {
      #pragma unroll
      for (int r=0;r<21;r++) ctreg[r] = 0.f;
    }

    // ---- U2: rows of P_pred ----
    col_update(ctreg, R_, n13, n23, dtv, hdt2, Gdt, Ghdt2);

    // ---- per-lane PHt row (sparse treed dots) ----
    float ph0 = (((ctreg[3]*h0_3 + ctreg[4]*h0_4) + (ctreg[5]*h0_5 + ctreg[9]*h0_9)) +
                 ((ctreg[11]*h0_11 + ctreg[15]*h0_15) + (ctreg[16]*h0_16 + ctreg[17]*h0_17))) +
                (ctreg[18]*h0_18 + ctreg[20]*h0_20);
    float ph1 = (((ctreg[3]*h1_3 + ctreg[4]*h1_4) + (ctreg[5]*h1_5 + ctreg[9]*h1_9)) +
                 ((ctreg[10]*h1_10 + ctreg[15]*h1_15) + (ctreg[16]*h1_16 + ctreg[17]*h1_17))) +
                (ctreg[18]*h1_18 + ctreg[19]*h1_19);
    if (lane<21) *(float2*)&PH[lane*2] = make_float2(ph0, ph1);

    // ---- PH read (uniform broadcast) ----
    float pj0[21], pj1[21];
    {
      #pragma unroll
      for (int q=0;q<11;q++){
        float4 v4 = ((float4*)PH)[q];
        if (2*q   < 21){ pj0[2*q]   = v4.x; pj1[2*q]   = v4.y; }
        if (2*q+1 < 21){ pj0[2*q+1] = v4.z; pj1[2*q+1] = v4.w; }
      }
    }

    // ---- S (sparse treed), inverse, gains (uniform) ----
    float s00 = mc0 + ((((h0_3*pj0[3] + h0_4*pj0[4]) + (h0_5*pj0[5] + h0_9*pj0[9])) +
                        ((h0_11*pj0[11] + h0_15*pj0[15]) + (h0_16*pj0[16] + h0_17*pj0[17]))) +
                       (h0_18*pj0[18] + h0_20*pj0[20]));
    float s01 =        ((((h0_3*pj1[3] + h0_4*pj1[4]) + (h0_5*pj1[5] + h0_9*pj1[9])) +
                        ((h0_11*pj1[11] + h0_15*pj1[15]) + (h0_16*pj1[16] + h0_17*pj1[17]))) +
                       (h0_18*pj1[18] + h0_20*pj1[20]));
    float s10 =        ((((h1_3*pj0[3] + h1_4*pj0[4]) + (h1_5*pj0[5] + h1_9*pj0[9])) +
                        ((h1_10*pj0[10] + h1_15*pj0[15]) + (h1_16*pj0[16] + h1_17*pj0[17]))) +
                       (h1_18*pj0[18] + h1_19*pj0[19]));
    float s11 = mc1 + ((((h1_3*pj1[3] + h1_4*pj1[4]) + (h1_5*pj1[5] + h1_9*pj1[9])) +
                        ((h1_10*pj1[10] + h1_15*pj1[15]) + (h1_16*pj1[16] + h1_17*pj1[17]))) +
                       (h1_18*pj1[18] + h1_19*pj1[19]));
    float id  = 1.f/(s00*s11 - s01*s10);
    float i00 =  s11*id, i01 = -s01*id, i10 = -s10*id, i11 = s00*id;
    float sm01 = 0.5f*(s01+s10);
    float g0 = i00*rsh0 + i01*rsh1;
    float g1 = i10*rsh0 + i11*rsh1;

    // ---- dx (uniform) ----
    float dx[21];
    #pragma unroll
    for (int j=0;j<21;j++) dx[j] = pj0[j]*g0 + pj1[j]*g1;

    // ---- per-lane alpha/beta; rank-2 fold ----
    {
      float ki0 = ph0*i00 + ph1*i10;
      float ki1 = ph0*i01 + ph1*i11;
      float ai0 = s00*ki0 + sm01*ki1;
      float ai1 = sm01*ki0 + s11*ki1;
      float al = -ki0 + (ai0 - ph0)*i00 + (ai1 - ph1)*i01;
      float be = -ki1 + (ai0 - ph0)*i10 + (ai1 - ph1)*i11;
      #pragma unroll
      for (int j=0;j<21;j++) creg[j] = ctreg[j] + al*pj0[j] + be*pj1[j];
    }

    // ---- retraction (uniform) ----
    {
      float q0=dx[0], q1=dx[1], q2=dx[2];
      float a2 = q0*q0+q1*q1+q2*q2;
      float c1,c2,c3; so3coeffs(a2,&c1,&c2,&c3);
      float dR[9], Jm[9];
      dR[0]=1.f+c2*(q0*q0-a2); dR[4]=1.f+c2*(q1*q1-a2); dR[8]=1.f+c2*(q2*q2-a2);
      dR[1]=-c1*q2+c2*q0*q1;   dR[3]= c1*q2+c2*q0*q1;
      dR[2]= c1*q1+c2*q0*q2;   dR[6]=-c1*q1+c2*q0*q2;
      dR[5]=-c1*q0+c2*q1*q2;   dR[7]= c1*q0+c2*q1*q2;
      Jm[0]=1.f+c3*(q0*q0-a2); Jm[4]=1.f+c3*(q1*q1-a2); Jm[8]=1.f+c3*(q2*q2-a2);
      Jm[1]=-c2*q2+c3*q0*q1;   Jm[3]= c2*q2+c3*q0*q1;
      Jm[2]= c2*q1+c3*q0*q2;   Jm[6]=-c2*q1+c3*q0*q2;
      Jm[5]=-c2*q0+c3*q1*q2;   Jm[7]= c2*q0+c3*q1*q2;
      float xv[3], xp[3];
      #pragma unroll
      for (int r=0;r<3;r++){
        xv[r]=Jm[r*3]*dx[3]+Jm[r*3+1]*dx[4]+Jm[r*3+2]*dx[5];
        xp[r]=Jm[r*3]*dx[6]+Jm[r*3+1]*dx[7]+Jm[r*3+2]*dx[8];
      }
      float Rn2[9]; mat3mul_u(dR, Rn, Rn2);
      #pragma unroll
      for (int r=0;r<3;r++){
        float vv2 = dR[r*3]*vnp[0]+dR[r*3+1]*vnp[1]+dR[r*3+2]*vnp[2] + xv[r];
        float pp2 = dR[r*3]*pnp[0]+dR[r*3+1]*pnp[1]+dR[r*3+2]*pnp[2] + xp[r];
        v_[r]=vv2; p_[r]=pp2;
        bo_[r]+=dx[9+r]; ba_[r]+=dx[12+r]; tci_[r]+=dx[18+r];
      }
      float E2[9]; so3exp_u(dx[15],dx[16],dx[17],E2);
      float Rc2[9]; mat3mul_u(E2, Rci_, Rc2);
      #pragma unroll
      for (int k=0;k<9;k++){ Rci_[k]=Rc2[k]; R_[k]=Rn2[k]; }
    }
    // commit state (lane 0)
    if (lane==0){
      ((float4*)stG)[0] = make_float4(R_[0],R_[1],R_[2],R_[3]);
      ((float4*)stG)[1] = make_float4(R_[4],R_[5],R_[6],R_[7]);
      ((float4*)stG)[2] = make_float4(R_[8],v_[0],v_[1],v_[2]);
      ((float4*)stG)[3] = make_float4(p_[0],p_[1],p_[2],bo_[0]);
      ((float4*)stG)[4] = make_float4(bo_[1],bo_[2],ba_[0],ba_[1]);
      ((float4*)stG)[5] = make_float4(ba_[2],Rci_[0],Rci_[1],Rci_[2]);
      ((float4*)stG)[6] = make_float4(Rci_[3],Rci_[4],Rci_[5],Rci_[6]);
      ((float4*)stG)[7] = make_float4(Rci_[7],Rci_[8],tci_[0],tci_[1]);
      ((float4*)stG)[8] = make_float4(tci_[2],0.f,0.f,0.f);
    }

    // ---- prefetch next inputs (uniform) ----
    {
      int np = n+1;
      t_nm1 = t_n;
      if (np < N){
        t_n = t[np];
        mc0 = mcov[np*2]; mc1 = mcov[np*2+1];
        #pragma unroll
        for (int k=0;k<6;k++) u6[k]=u[np*6+k];
      }
    }
  }

  // final output row
  if (lane<33) out[(size_t)(N-1)*33 + lane] = stG[lane];
}

extern "C" void kernel_launch(void* const* d_in, const int* in_sizes, int n_in,
                              void* d_out, int out_size, void* d_ws, size_t ws_size,
                              hipStream_t stream) {
  const float* t     = (const float*)d_in[0];
  const float* u     = (const float*)d_in[1];
  const float* mcov  = (const float*)d_in[2];
  const float* vmes  = (const float*)d_in[3];
  // d_in[4] = p_mes (unused by reference)
  const float* ang0  = (const float*)d_in[5];
  const float* winit = (const float*)d_in[6];
  float* out = (float*)d_out;
  int N = in_sizes[0];
  iekf_kernel<<<dim3(1), dim3(64), 0, stream>>>(t, u, mcov, vmes, ang0, winit, out, N);
}